// Round 16
// baseline (154.132 us; speedup 1.0000x reference)
//
#include <hip/hip_runtime.h>
#include <hip/hip_bf16.h>

#define B_ 2
#define S_ 1024
#define F_ 1024
#define H_ 8
#define D_ 64
#define R_ 2
#define BH (B_*H_)
#define NC 16        // combine chunks (64 tokens)
#define NCT 32       // transfer chunks
#define CT (S_/NCT)  // 32 tokens per transfer chunk

// combined projection layout: [M, NPROJ] fp32
#define QOFF 0
#define KOFF 512
#define VOFF 1536
#define BOFF 2560
#define NPROJ 2624   // 41 * 64

typedef __bf16 bf16x8 __attribute__((ext_vector_type(8)));
typedef unsigned short ushort8 __attribute__((ext_vector_type(8)));
typedef float f32x4 __attribute__((ext_vector_type(4)));

__device__ __forceinline__ unsigned short f2bf(float f) {
    unsigned u = __builtin_bit_cast(unsigned, f);
    unsigned r = u + 0x7FFFu + ((u >> 16) & 1u);
    return (unsigned short)(r >> 16);
}

__device__ __forceinline__ void gload_lds16(const void* g, void* l) {
    __builtin_amdgcn_global_load_lds(
        (const __attribute__((address_space(1))) void*)g,
        (__attribute__((address_space(3))) void*)l, 16, 0, 0);
}

// DPP lane swaps (VALU pipe).
template<int CTRL>
__device__ __forceinline__ float dppf(float x) {
    return __builtin_bit_cast(float, __builtin_amdgcn_update_dpp(
        0, __builtin_bit_cast(int, x), CTRL, 0xF, 0xF, true));
}
__device__ __forceinline__ float qsum8(float x) {
    x += dppf<0xB1>(x);
    x += dppf<0x4E>(x);
    x += dppf<0x141>(x);
    return x;
}

// ------------------------------------------------------------------
// Mask format sniffer + normalize to float 0/1.
// ------------------------------------------------------------------
__global__ void k_mask_prep(const void* __restrict__ mraw, float* __restrict__ maskf, int n) {
    __shared__ int fmt;
    int t = threadIdx.x;
    if (t == 0) fmt = 0;
    __syncthreads();
    const unsigned int* u32 = (const unsigned int*)mraw;
    for (int g = t; g < n / 4; g += blockDim.x) {
        unsigned int v = u32[g];
        if (v == 0x3F800000u) atomicMax(&fmt, 2);
        else if (v != 0u && v != 1u) atomicMax(&fmt, 1);
    }
    __syncthreads();
    int f = fmt;
    const unsigned char* u8 = (const unsigned char*)mraw;
    const float* f32 = (const float*)mraw;
    for (int i = t; i < n; i += blockDim.x) {
        float mv;
        if (f == 1)      mv = u8[i] ? 1.f : 0.f;
        else if (f == 2) mv = (f32[i] != 0.f) ? 1.f : 0.f;
        else             mv = (u32[i] != 0u) ? 1.f : 0.f;
        maskf[i] = mv;
    }
}

// ------------------------------------------------------------------
__global__ void k_f32_to_bf16(const float* __restrict__ s, unsigned short* __restrict__ d, int n) {
    int i = (blockIdx.x * blockDim.x + threadIdx.x) * 4;
    if (i < n) {
        float4 v = *(const float4*)&s[i];
        d[i + 0] = f2bf(v.x); d[i + 1] = f2bf(v.y);
        d[i + 2] = f2bf(v.z); d[i + 3] = f2bf(v.w);
    }
}

// ------------------------------------------------------------------
__global__ __launch_bounds__(256) void k_transpose_to_bf16(
    const float* __restrict__ src, unsigned short* __restrict__ dst, int K, int N)
{
    __shared__ float tile[32][33];
    int bx = blockIdx.x, by = blockIdx.y;
    int tx = threadIdx.x & 31, ty = threadIdx.x >> 5;
#pragma unroll
    for (int i = 0; i < 32; i += 8)
        tile[ty + i][tx] = src[(size_t)(by * 32 + ty + i) * N + bx * 32 + tx];
    __syncthreads();
#pragma unroll
    for (int i = 0; i < 32; i += 8)
        dst[(size_t)(bx * 32 + ty + i) * K + by * 32 + tx] = f2bf(tile[tx][ty + i]);
}

// ------------------------------------------------------------------
__global__ void k_wb_pad(const float* __restrict__ Wb, unsigned short* __restrict__ dst) {
    int row = blockIdx.x;
    int c0 = threadIdx.x * 4;
#pragma unroll
    for (int c = c0; c < c0 + 4; ++c)
        dst[(size_t)row * 1024 + c] = (row < 16) ? f2bf(Wb[(size_t)c * 16 + row]) : (unsigned short)0;
}

// ------------------------------------------------------------------
// bf16 MFMA GEMM: C[M,N] = A[M,K] @ B[K,N] (+bias). Tile 128x64, BK=64.
// ------------------------------------------------------------------
__global__ __launch_bounds__(256) void k_gemm_bf16(
    const unsigned short* __restrict__ A, const unsigned short* __restrict__ Bt,
    const float* __restrict__ bias, float* __restrict__ C,
    int M, int N, int K)
{
    constexpr int BM = 128, BN = 64, BK = 64;
    __shared__ unsigned short sA[BM * BK];
    __shared__ unsigned short sB[BN * BK];
    int t = threadIdx.x;
    int w = t >> 6, l = t & 63;
    int rowb = blockIdx.y * BM, colb = blockIdx.x * BN;
    int wr = w >> 1, wc = w & 1;
    int fr = l & 15, kgrp = l >> 4;

    f32x4 acc[4][2];
#pragma unroll
    for (int m = 0; m < 4; ++m)
#pragma unroll
        for (int n = 0; n < 2; ++n) acc[m][n] = (f32x4){0.f, 0.f, 0.f, 0.f};

    int lrow_off = l >> 3;
    int kg_phys = l & 7;

    for (int k0 = 0; k0 < K; k0 += BK) {
        __syncthreads();
#pragma unroll
        for (int is = 0; is < 4; ++is) {
            int r0 = (w * 4 + is) * 8;
            int row = r0 + lrow_off;
            int kg_log = kg_phys ^ (row & 7);
            gload_lds16(A + (size_t)(rowb + row) * K + k0 + kg_log * 8, &sA[r0 * BK]);
        }
#pragma unroll
        for (int is = 0; is < 2; ++is) {
            int r0 = (w * 2 + is) * 8;
            int row = r0 + lrow_off;
            int kg_log = kg_phys ^ (row & 7);
            gload_lds16(Bt + (size_t)(colb + row) * K + k0 + kg_log * 8, &sB[r0 * BK]);
        }
        asm volatile("s_waitcnt vmcnt(0)" ::: "memory");
        __syncthreads();

#pragma unroll
        for (int kk = 0; kk < BK; kk += 32) {
            int kg = (kk >> 3) + kgrp;
            bf16x8 af[4], bfv[2];
#pragma unroll
            for (int m = 0; m < 4; ++m) {
                int row = wr * 64 + m * 16 + fr;
                ushort8 raw = *(const ushort8*)&sA[row * BK + (kg ^ (row & 7)) * 8];
                af[m] = __builtin_bit_cast(bf16x8, raw);
            }
#pragma unroll
            for (int n = 0; n < 2; ++n) {
                int row = wc * 32 + n * 16 + fr;
                ushort8 raw = *(const ushort8*)&sB[row * BK + (kg ^ (row & 7)) * 8];
                bfv[n] = __builtin_bit_cast(bf16x8, raw);
            }
#pragma unroll
            for (int m = 0; m < 4; ++m)
#pragma unroll
                for (int n = 0; n < 2; ++n)
                    acc[m][n] = __builtin_amdgcn_mfma_f32_16x16x32_bf16(af[m], bfv[n], acc[m][n], 0, 0, 0);
        }
    }

#pragma unroll
    for (int m = 0; m < 4; ++m)
#pragma unroll
        for (int n = 0; n < 2; ++n) {
            int grow0 = rowb + wr * 64 + m * 16 + kgrp * 4;
            int gcol  = colb + wc * 32 + n * 16 + fr;
            float bv = bias ? bias[gcol] : 0.f;
#pragma unroll
            for (int r = 0; r < 4; ++r)
                C[(size_t)(grow0 + r) * N + gcol] = acc[m][n][r] + bv;
        }
}

// ------------------------------------------------------------------
__global__ void k_silu_norm(float* __restrict__ buf, int ngroups,
                            int gshift, int gmask, int rowstride, int coloff) {
    int w = threadIdx.x >> 6;
    int l = threadIdx.x & 63;
    int g = blockIdx.x * 4 + w;
    if (g >= ngroups) return;
    size_t idx = (size_t)(g >> gshift) * rowstride + coloff + ((g & gmask) << 6) + l;
    float x = buf[idx];
    float s = x / (1.f + expf(-x));
    float ss = s * s;
#pragma unroll
    for (int m = 1; m < 64; m <<= 1) ss += __shfl_xor(ss, m);
    float nrm = sqrtf(ss) + 1e-6f;
    buf[idx] = s / nrm;
}

// ------------------------------------------------------------------
// Phase 1: per (bh, 32-token chunk): transfer ops (Ac32, Bc32) AND
// per-token a_s, b_s (-> ab). R12 structure at half serial depth:
// 1024 threads, 8 lanes/state row, 512 blocks -> 8 waves/SIMD.
// ------------------------------------------------------------------
__global__ __launch_bounds__(1024) void k_chunk_transfer(
    const float* __restrict__ proj, const float* __restrict__ maskf,
    float* __restrict__ Ac, float* __restrict__ Bc, float* __restrict__ ab)
{
    int c = blockIdx.x;        // 0..NCT-1
    int bh = blockIdx.y;
    int b = bh >> 3, h = bh & 7;
    int t = threadIdx.x;
    int half = t >> 9;         // 0 = A-state, 1 = B-state
    int tt = t & 511;
    int i = tt >> 3;           // state row 0..63
    int sub = tt & 7;
    int e0 = sub * 8;
    __shared__ float sK[CT][128];     // 16 KB
    __shared__ float sQ[CT][64];      // 8 KB
    __shared__ float4 sScal[CT];
    __shared__ float4 sDots[CT];

    size_t tokbase = (size_t)(b * S_ + c * CT);
    {   // stage K: CT*32 = 1024 float4, one per thread
        int tok = t >> 5, wi = t & 31;
        *(float4*)&sK[tok][wi * 4] = *(const float4*)&proj[(tokbase + tok) * NPROJ + KOFF + h * 128 + wi * 4];
    }
    if (t < CT * 16) {   // stage Q: 512 float4
        int tok = t >> 4, wi = t & 15;
        *(float4*)&sQ[tok][wi * 4] = *(const float4*)&proj[(tokbase + tok) * NPROJ + QOFF + h * 64 + wi * 4];
    }
    if (t < CT) {
        float r0 = proj[(tokbase + t) * NPROJ + BOFF + h * 2 + 0];
        float r1 = proj[(tokbase + t) * NPROJ + BOFF + h * 2 + 1];
        float ms = 1.f - maskf[tokbase + t];
        sScal[t] = make_float4(1.f / (1.f + expf(-r0)), 1.f / (1.f + expf(-r1)), ms, 0.f);
    }
    __syncthreads();

    // token-scalars: 8 threads per token (first 256 threads)
    if (t < CT * 8) {
        int tok = t >> 3, s8 = (t & 7) * 8;
        float p01 = 0.f, p0q = 0.f, p1q = 0.f;
#pragma unroll
        for (int e = 0; e < 8; ++e) {
            float k0e = sK[tok][s8 + e];
            float k1e = sK[tok][64 + s8 + e];
            float qe  = sQ[tok][s8 + e];
            p01 = fmaf(k0e, k1e, p01);
            p0q = fmaf(k0e, qe,  p0q);
            p1q = fmaf(k1e, qe,  p1q);
        }
        p01 = qsum8(p01); p0q = qsum8(p0q); p1q = qsum8(p1q);
        if ((t & 7) == 0) sDots[tok] = make_float4(p01, p0q, p1q, 0.f);
    }
    __syncthreads();

    float St[8];
#pragma unroll
    for (int j = 0; j < 8; ++j)
        St[j] = (half == 0 && e0 + j == i) ? 1.f : 0.f;

    const float* vbase = &proj[tokbase * NPROJ + VOFF + h * 128];
    float v0 = 0.f, v1 = 0.f;
    if (half) { v0 = vbase[i]; v1 = vbase[64 + i]; }

    float* abdst = ab + ((size_t)bh * NCT + c) * (size_t)(CT * 128) + half * 64 + i;

    for (int sl = 0; sl < CT; ++sl) {
        float vc0 = v0, vc1 = v1;
        if (half && sl + 1 < CT) {
            const float* nb = vbase + (size_t)(sl + 1) * NPROJ;
            v0 = nb[i]; v1 = nb[64 + i];
        }
        float4 sc = sScal[sl];
        float4 dt = sDots[sl];
        if (sc.z == 0.f) {
#pragma unroll
            for (int j = 0; j < 8; ++j) St[j] = 0.f;
        }
        float k0[8], k1[8], qq[8];
        *(float4*)&k0[0] = *(const float4*)&sK[sl][e0];
        *(float4*)&k0[4] = *(const float4*)&sK[sl][e0 + 4];
        *(float4*)&k1[0] = *(const float4*)&sK[sl][64 + e0];
        *(float4*)&k1[4] = *(const float4*)&sK[sl][64 + e0 + 4];
        *(float4*)&qq[0] = *(const float4*)&sQ[sl][e0];
        *(float4*)&qq[4] = *(const float4*)&sQ[sl][e0 + 4];
        float a0 = 0.f, a1 = 0.f, b0 = 0.f, b1 = 0.f, c0v = 0.f, c1v = 0.f;
#pragma unroll
        for (int q = 0; q < 4; ++q) {
            a0 = fmaf(St[q],     k0[q],     a0);
            a1 = fmaf(St[4 + q], k0[4 + q], a1);
            b0 = fmaf(St[q],     k1[q],     b0);
            b1 = fmaf(St[4 + q], k1[4 + q], b1);
            c0v = fmaf(St[q],     qq[q],     c0v);
            c1v = fmaf(St[4 + q], qq[4 + q], c1v);
        }
        float d0 = qsum8(a0 + a1);
        float d1 = qsum8(b0 + b1);
        float dq = qsum8(c0v + c1v);
        float c0, c1;
        if (half == 0) {
            c0 = -sc.x * d0;
            float u1 = fmaf(c0, dt.x, d1);
            c1 = -sc.y * u1;
        } else {
            c0 = sc.x * (vc0 - d0);
            float u1 = fmaf(c0, dt.x, d1);
            c1 = sc.y * (vc1 - u1);
        }
        float xv = fmaf(c1, dt.z, fmaf(c0, dt.y, dq));
        if (sub == 0) abdst[sl * 128] = xv;
#pragma unroll
        for (int j = 0; j < 8; ++j) {
            St[j] = fmaf(c0, k0[j], St[j]);
            St[j] = fmaf(c1, k1[j], St[j]);
        }
    }
    float* dst = (half == 0 ? Ac : Bc) + ((size_t)bh * NCT + c) * 4096 + (size_t)i * 64 + e0;
    *(float4*)&dst[0] = make_float4(St[0], St[1], St[2], St[3]);
    *(float4*)&dst[4] = make_float4(St[4], St[5], St[6], St[7]);
}

// ------------------------------------------------------------------
// Stage 4096 floats from global into padded [64][68] LDS.
// ------------------------------------------------------------------
__device__ __forceinline__ void stage_padded(const float* __restrict__ g, float* lds, int t) {
#pragma unroll
    for (int s = 0; s < 4; ++s) {
        int f = s * 256 + t;
        float4 v = *(const float4*)&g[(size_t)f * 4];
        int r = f >> 4, c = (f & 15) * 4;
        *(float4*)&lds[r * 68 + c] = v;
    }
}

// ------------------------------------------------------------------
// Merge pairs of 32-token ops into 64-token ops:
//   A16[g] = A32[2g]·A32[2g+1];  B16[g] = B32[2g]·A32[2g+1] + B32[2g+1]
// grid (16, BH), 256 threads; thread: row i=t>>2, cols (t&3)*16..+15.
// ------------------------------------------------------------------
__global__ __launch_bounds__(256) void k_merge(
    const float* __restrict__ Ac32, const float* __restrict__ Bc32,
    float* __restrict__ Ac16, float* __restrict__ Bc16)
{
    int g = blockIdx.x, bh = blockIdx.y;
    size_t li = ((size_t)bh * NCT + 2 * g) * 4096;
    size_t ri = li + 4096;
    int t = threadIdx.x;
    int i = t >> 2, j0 = (t & 3) * 16;
    __shared__ float sAl[64 * 68];
    __shared__ float sBl[64 * 68];
    __shared__ float sAr[4096];

#pragma unroll
    for (int s = 0; s < 4; ++s)
        gload_lds16(Ac32 + ri + (size_t)(s * 256 + t) * 4, &sAr[(size_t)(s * 256 + (t & 192)) * 4]);
    stage_padded(Ac32 + li, sAl, t);
    stage_padded(Bc32 + li, sBl, t);
    float4 aB[4], aA[4];
#pragma unroll
    for (int q = 0; q < 4; ++q) {
        aB[q] = *(const float4*)&Bc32[ri + (size_t)i * 64 + j0 + q * 4];
        aA[q] = make_float4(0.f, 0.f, 0.f, 0.f);
    }
    asm volatile("s_waitcnt vmcnt(0)" ::: "memory");
    __syncthreads();

#pragma unroll 4
    for (int pp = 0; pp < 64; ++pp) {
        float la = sAl[i * 68 + pp];
        float lb = sBl[i * 68 + pp];
#pragma unroll
        for (int q = 0; q < 4; ++q) {
            float4 ar = *(const float4*)&sAr[pp * 64 + j0 + q * 4];
            aA[q].x = fmaf(la, ar.x, aA[q].x); aA[q].y = fmaf(la, ar.y, aA[q].y);
            aA[q].z = fmaf(la, ar.z, aA[q].z); aA[q].w = fmaf(la, ar.w, aA[q].w);
            aB[q].x = fmaf(lb, ar.x, aB[q].x); aB[q].y = fmaf(lb, ar.y, aB[q].y);
            aB[q].z = fmaf(lb, ar.z, aB[q].z); aB[q].w = fmaf(lb, ar.w, aB[q].w);
        }
    }
    size_t od = ((size_t)bh * NC + g) * 4096 + (size_t)i * 64 + j0;
#pragma unroll
    for (int q = 0; q < 4; ++q) {
        *(float4*)&Ac16[od + q * 4] = aA[q];
        *(float4*)&Bc16[od + q * 4] = aB[q];
    }
}

// ------------------------------------------------------------------
// Phase 2: sequential NC=16 combine (proven structure). S0 for the
// 64-token chunk g is written into DEAD Ac32 slot (2g+1).
// ------------------------------------------------------------------
__global__ __launch_bounds__(256) void k_combine(
    const float* __restrict__ Ac, const float* __restrict__ Bc,
    const float* __restrict__ carry, float* __restrict__ S0ac,
    float* __restrict__ carry_out)
{
    constexpr int SP = 68;
    int blk = blockIdx.x;
    int bh = blk >> 2, rg = blk & 3;
    int t = threadIdx.x;
    int i = t >> 4;
    int j0 = (t & 15) * 4;
    int gi = rg * 16 + i;
    __shared__ float sA[2][64 * 64];
    __shared__ float sS[16 * SP];

    size_t cb0 = (size_t)bh * NC * 4096;
#pragma unroll
    for (int s = 0; s < 4; ++s)
        gload_lds16(Ac + cb0 + (size_t)(s * 256 + t) * 4, &sA[0][(size_t)(s * 256 + (t & 192)) * 4]);
    float4 rB = *(const float4*)&Bc[cb0 + (size_t)gi * 64 + j0];
    float4 racc = *(const float4*)&carry[(size_t)bh * 4096 + (size_t)gi * 64 + j0];
    *(float4*)&sS[i * SP + j0] = racc;
    asm volatile("s_waitcnt vmcnt(0)" ::: "memory");
    __syncthreads();

    for (int c = 0; c < NC; ++c) {
        int cur = c & 1;
        size_t cb = cb0 + (size_t)c * 4096;
        float4 rBn;
        if (c + 1 < NC) {
#pragma unroll
            for (int s = 0; s < 4; ++s)
                gload_lds16(Ac + cb + 4096 + (size_t)(s * 256 + t) * 4,
                            &sA[cur ^ 1][(size_t)(s * 256 + (t & 192)) * 4]);
            rBn = *(const float4*)&Bc[cb + 4096 + (size_t)gi * 64 + j0];
        }
        // S0_16[c] -> Ac32 slot 2c+1 (dead after merge)
        *(float4*)&S0ac[((size_t)bh * NCT + 2 * c + 1) * 4096 + (size_t)gi * 64 + j0] = racc;
        float4 acc = rB;
        float4 ac2 = make_float4(0.f, 0.f, 0.f, 0.f);
#pragma unroll
        for (int p4 = 0; p4 < 16; p4 += 2) {
            float4 s0v = *(const float4*)&sS[i * SP + p4 * 4];
            float4 s1v = *(const float4*)&sS[i * SP + p4 * 4 + 4];
            float4 a0 = *(const float4*)&sA[cur][(p4 * 4 + 0) * 64 + j0];
            float4 a1 = *(const float4*)&sA[cur][(p4 * 4 + 1) * 64 + j0];
            float4 a2 = *(const float4*)&sA[cur][(p4 * 4 + 2) * 64 + j0];
            float4 a3 = *(const float4*)&sA[cur][(p4 * 4 + 3) * 64 + j0];
            float4 a4 = *(const float4*)&sA[cur][(p4 * 4 + 4) * 64 + j0];
            float4 a5 = *(const float4*)&sA[cur][(p4 * 4 + 5) * 64 + j0];
            float4 a6 = *(const float4*)&sA[cur][(p4 * 4 + 6) * 64 + j0];
            float4 a7 = *(const float4*)&sA[cur][(p4 * 4 + 7) * 64 + j0];
            acc.x = fmaf(s0v.x, a0.x, acc.x); acc.y = fmaf(s0v.x, a0.y, acc.y);
            acc.z = fmaf(s0v.x, a0.z, acc.z); acc.w = fmaf(s0v.x, a0.w, acc.w);
            ac2.x = fmaf(s0v.y, a1.x, ac2.x); ac2.y = fmaf(s0v.y, a1.y, ac2.y);
            ac2.z = fmaf(s0v.y, a1.z, ac2.z); ac2.w = fmaf(s0v.y, a1.w, ac2.w);
            acc.x = fmaf(s0v.z, a2.x, acc.x); acc.y = fmaf(s0v.z, a2.y, acc.y);
            acc.z = fmaf(s0v.z, a2.z, acc.z); acc.w = fmaf(s0v.z, a2.w, acc.w);
            ac2.x = fmaf(s0v.w, a3.x, ac2.x); ac2.y = fmaf(s0v.w, a3.y, ac2.y);
            ac2.z = fmaf(s0v.w, a3.z, ac2.z); ac2.w = fmaf(s0v.w, a3.w, ac2.w);
            acc.x = fmaf(s1v.x, a4.x, acc.x); acc.y = fmaf(s1v.x, a4.y, acc.y);
            acc.z = fmaf(s1v.x, a4.z, acc.z); acc.w = fmaf(s1v.x, a4.w, acc.w);
            ac2.x = fmaf(s1v.y, a5.x, ac2.x); ac2.y = fmaf(s1v.y, a5.y, ac2.y);
            ac2.z = fmaf(s1v.y, a5.z, ac2.z); ac2.w = fmaf(s1v.y, a5.w, ac2.w);
            acc.x = fmaf(s1v.z, a6.x, acc.x); acc.y = fmaf(s1v.z, a6.y, acc.y);
            acc.z = fmaf(s1v.z, a6.z, acc.z); acc.w = fmaf(s1v.z, a6.w, acc.w);
            ac2.x = fmaf(s1v.w, a7.x, ac2.x); ac2.y = fmaf(s1v.w, a7.y, ac2.y);
            ac2.z = fmaf(s1v.w, a7.z, ac2.z); ac2.w = fmaf(s1v.w, a7.w, ac2.w);
        }
        acc.x += ac2.x; acc.y += ac2.y; acc.z += ac2.z; acc.w += ac2.w;
        __syncthreads();
        *(float4*)&sS[i * SP + j0] = acc;
        racc = acc;
        rB = rBn;
        asm volatile("s_waitcnt vmcnt(0)" ::: "memory");
        __syncthreads();
    }
    *(float4*)&carry_out[(size_t)bh * 4096 + (size_t)gi * 64 + j0] = racc;
}

// ------------------------------------------------------------------
// Fixup: S0_32[2g+1] = S0_16[g]·A32[2g] + B32[2g], written into the
// (consumed) Ac32 slot 2g. After this, S0 for transfer chunk c lives
// at Ac32 slot (c^1). grid (16, BH).
// ------------------------------------------------------------------
__global__ __launch_bounds__(256) void k_fixup(
    float* __restrict__ Ac32, const float* __restrict__ Bc32)
{
    int g = blockIdx.x, bh = blockIdx.y;
    int t = threadIdx.x;
    int i = t >> 2, j0 = (t & 3) * 16;
    size_t sEven = ((size_t)bh * NCT + 2 * g) * 4096;       // A32 left / out
    size_t sOdd  = sEven + 4096;                            // S0_16[g]
    __shared__ float sS[64 * 68];
    __shared__ float sA[4096];

#pragma unroll
    for (int s = 0; s < 4; ++s)
        gload_lds16(Ac32 + sEven + (size_t)(s * 256 + t) * 4, &sA[(size_t)(s * 256 + (t & 192)) * 4]);
    stage_padded(Ac32 + sOdd, sS, t);
    float4 acc[4];
#pragma unroll
    for (int q = 0; q < 4; ++q)
        acc[q] = *(const float4*)&Bc32[sEven + (size_t)i * 64 + j0 + q * 4];
    asm volatile("s_waitcnt vmcnt(0)" ::: "memory");
    __syncthreads();

#pragma unroll 4
    for (int pp = 0; pp < 64; ++pp) {
        float s = sS[i * 68 + pp];
#pragma unroll
        for (int q = 0; q < 4; ++q) {
            float4 ar = *(const float4*)&sA[pp * 64 + j0 + q * 4];
            acc[q].x = fmaf(s, ar.x, acc[q].x); acc[q].y = fmaf(s, ar.y, acc[q].y);
            acc[q].z = fmaf(s, ar.z, acc[q].z); acc[q].w = fmaf(s, ar.w, acc[q].w);
        }
    }
#pragma unroll
    for (int q = 0; q < 4; ++q)
        *(float4*)&Ac32[sEven + (size_t)i * 64 + j0 + q * 4] = acc[q];
}

// ------------------------------------------------------------------
// Phase 3: X = Aa·S0^T + Bb per (bh, 32-token chunk). S0 for chunk c
// is at Ac32 slot (c^1). grid (32, BH), 256 threads: 2 tokens x 4 dims.
// ------------------------------------------------------------------
__global__ __launch_bounds__(256) void k_xgemm(
    const float* __restrict__ ab, const float* __restrict__ S0ac,
    float* __restrict__ proj)
{
    int c = blockIdx.x, bh = blockIdx.y;
    int b = bh >> 3, h = bh & 7;
    int t = threadIdx.x;
    __shared__ float sAaT[64 * 33];   // Aa^T : [p][s], s in 0..31
    __shared__ float sS0T[64 * 67];   // S0^T : [p][i]
    size_t abbase = ((size_t)bh * NCT + c) * (size_t)(CT * 128);
    size_t s0base = ((size_t)bh * NCT + (c ^ 1)) * 4096;

#pragma unroll
    for (int it = 0; it < 2; ++it) {   // Aa: 32 tok x 16 f4 = 512
        int f = it * 256 + t;
        int r = f >> 4, p0 = (f & 15) * 4;
        float4 va = *(const float4*)&ab[abbase + (size_t)r * 128 + p0];
        sAaT[(p0 + 0) * 33 + r] = va.x; sAaT[(p0 + 1) * 33 + r] = va.y;
        sAaT[(p0 + 2) * 33 + r] = va.z; sAaT[(p0 + 3) * 33 + r] = va.w;
    }
#pragma unroll
    for (int it = 0; it < 4; ++it) {   // S0: 64 x 16 f4 = 1024
        int f = it * 256 + t;
        int r = f >> 4, p0 = (f & 15) * 4;
        float4 vs = *(const float4*)&S0ac[s0base + (size_t)r * 64 + p0];
        sS0T[(p0 + 0) * 67 + r] = vs.x; sS0T[(p0 + 1) * 67 + r] = vs.y;
        sS0T[(p0 + 2) * 67 + r] = vs.z; sS0T[(p0 + 3) * 67 + r] = vs.w;
    }
    __syncthreads();

    int s0r = (t >> 4) * 2;     // 2 tokens
    int i0 = (t & 15) * 4;      // 4 dims
    size_t tokbase = (size_t)(b * S_ + c * CT);
    float4 acc[2];
#pragma unroll
    for (int a = 0; a < 2; ++a)
        acc[a] = *(const float4*)&ab[abbase + (size_t)(s0r + a) * 128 + 64 + i0];
#pragma unroll 8
    for (int p = 0; p < 64; ++p) {
        float aa0 = sAaT[p * 33 + s0r];
        float aa1 = sAaT[p * 33 + s0r + 1];
        float4 ss = *(const float4*)&sS0T[p * 67 + i0];
        acc[0].x = fmaf(aa0, ss.x, acc[0].x); acc[0].y = fmaf(aa0, ss.y, acc[0].y);
        acc[0].z = fmaf(aa0, ss.z, acc[0].z); acc[0].w = fmaf(aa0, ss.w, acc[0].w);
        acc[1].x = fmaf(aa1, ss.x, acc[1].x); acc[1].y = fmaf(aa1, ss.y, acc[1].y);
        acc[1].z = fmaf(aa1, ss.z, acc[1].z); acc[1].w = fmaf(aa1, ss.w, acc[1].w);
    }
#pragma unroll
    for (int a = 0; a < 2; ++a)
        *(float4*)&proj[(tokbase + s0r + a) * NPROJ + QOFF + h * 64 + i0] = acc[a];
}

// ------------------------------------------------------------------
// RMS norm over x = proj cols 0..511, * rms_scale, emit compact bf16.
// ------------------------------------------------------------------
__global__ void k_rms_bf16(const float* __restrict__ proj, const float* __restrict__ scale,
                           unsigned short* __restrict__ xo) {
    int w = threadIdx.x >> 6;
    int l = threadIdx.x & 63;
    size_t row = (size_t)blockIdx.x * 4 + w;
    float4 v0 = *(const float4*)&proj[row * NPROJ + l * 8];
    float4 v1 = *(const float4*)&proj[row * NPROJ + l * 8 + 4];
    float ss = v0.x * v0.x + v0.y * v0.y + v0.z * v0.z + v0.w * v0.w
             + v1.x * v1.x + v1.y * v1.y + v1.z * v1.z + v1.w * v1.w;
#pragma unroll
    for (int m = 1; m < 64; m <<= 1) ss += __shfl_xor(ss, m);
    float sc = rsqrtf(ss * (1.f / 512.f) + 1e-6f);
    float4 s0 = *(const float4*)&scale[l * 8];
    float4 s1 = *(const float4*)&scale[l * 8 + 4];
    ushort8 o;
    o[0] = f2bf(v0.x * sc * s0.x); o[1] = f2bf(v0.y * sc * s0.y);
    o[2] = f2bf(v0.z * sc * s0.z); o[3] = f2bf(v0.w * sc * s0.w);
    o[4] = f2bf(v1.x * sc * s1.x); o[5] = f2bf(v1.y * sc * s1.y);
    o[6] = f2bf(v1.z * sc * s1.z); o[7] = f2bf(v1.w * sc * s1.w);
    *(ushort8*)&xo[row * 512 + l * 8] = o;
}

// ------------------------------------------------------------------
extern "C" void kernel_launch(void* const* d_in, const int* in_sizes, int n_in,
                              void* d_out, int out_size, void* d_ws, size_t ws_size,
                              hipStream_t stream) {
    const float* inputs    = (const float*)d_in[0];
    const void*  mask      = d_in[1];
    const float* carry     = (const float*)d_in[2];
    const float* Wq        = (const float*)d_in[3];
    const float* Wk        = (const float*)d_in[4];
    const float* Wv        = (const float*)d_in[5];
    const float* Wb        = (const float*)d_in[6];
    const float* rms_scale = (const float*)d_in[7];
    const float* Wo        = (const float*)d_in[8];
    const float* bo        = (const float*)d_in[9];

    float* out_carry = (float*)d_out;
    float* out_y     = (float*)d_out + (size_t)B_ * H_ * D_ * D_;

    const int M = B_ * S_;  // 2048
    float* ws = (float*)d_ws;
    size_t o = 0;
    float* proj  = ws + o; o += (size_t)M * NPROJ;            // 5.37M f
    float* mf    = ws + o; o += (size_t)M;
    float* Ac32  = ws + o; o += (size_t)BH * NCT * 4096;      // 2M f
    float* Bc32  = ws + o; o += (size_t)BH * NCT * 4096;      // 2M f
    float* Ac16  = ws + o; o += (size_t)BH * NC * 4096;       // 1M f
    float* Bc16  = ws + o; o += (size_t)BH * NC * 4096;       // 1M f
    float* abuf  = ws + o; o += (size_t)BH * NCT * CT * 128;  // 2M f
    unsigned short* wt = (unsigned short*)(ws + o); o += (size_t)NPROJ * 512;
    // overlays (lifetimes disjoint):
    unsigned short* inb = (unsigned short*)Bc32;  // bf16 inputs, dead before transfer writes Bc32
    unsigned short* xbf = (unsigned short*)Ac16;  // rms output; Ac16 dead after combine

    k_mask_prep<<<1, 256, 0, stream>>>(mask, mf, M);
    k_f32_to_bf16<<<(M * 1024) / 1024, 256, 0, stream>>>(inputs, inb, M * 1024);

    // pack W^T = [Wq^T | Wk^T | Wv^T | Wb^T(pad to 64)] as [NPROJ,1024] bf16
    k_transpose_to_bf16<<<dim3(512 / 32, 1024 / 32), 256, 0, stream>>>(Wq, wt + (size_t)QOFF * 1024, 1024, 512);
    k_transpose_to_bf16<<<dim3(1024 / 32, 1024 / 32), 256, 0, stream>>>(Wk, wt + (size_t)KOFF * 1024, 1024, 1024);
    k_transpose_to_bf16<<<dim3(1024 / 32, 1024 / 32), 256, 0, stream>>>(Wv, wt + (size_t)VOFF * 1024, 1024, 1024);
    k_wb_pad<<<64, 256, 0, stream>>>(Wb, wt + (size_t)BOFF * 1024);

    // proj = inputs @ [Wq|Wk|Wv|Wb]
    k_gemm_bf16<<<dim3(NPROJ / 64, M / 128), 256, 0, stream>>>(inb, wt, nullptr, proj, M, NPROJ, 1024);

    // silu+L2norm on q (8 groups/row) and k (16 groups/row)
    k_silu_norm<<<(M * 8) / 4, 256, 0, stream>>>(proj, M * 8, 3, 7, NPROJ, QOFF);
    k_silu_norm<<<(M * 16) / 4, 256, 0, stream>>>(proj, M * 16, 4, 15, NPROJ, KOFF);

    // scan: 32-token transfer -> pair-merge -> NC=16 combine -> fixup -> xgemm
    k_chunk_transfer<<<dim3(NCT, BH), 1024, 0, stream>>>(proj, mf, Ac32, Bc32, abuf);
    k_merge<<<dim3(NC, BH), 256, 0, stream>>>(Ac32, Bc32, Ac16, Bc16);
    k_combine<<<BH * 4, 256, 0, stream>>>(Ac16, Bc16, carry, Ac32, out_carry);
    k_fixup<<<dim3(NC, BH), 256, 0, stream>>>(Ac32, Bc32);
    k_xgemm<<<dim3(NCT, BH), 256, 0, stream>>>(abuf, Ac32, proj);

    k_rms_bf16<<<M / 4, 256, 0, stream>>>(proj, rms_scale, xbf);

    // y = x @ Wo + bo  (K=512, N=1024); reuse wt for Wo^T
    k_transpose_to_bf16<<<dim3(1024 / 32, 512 / 32), 256, 0, stream>>>(Wo, wt, 512, 1024);
    k_gemm_bf16<<<dim3(1024 / 64, M / 128), 256, 0, stream>>>(xbf, wt, bo, out_y, M, 1024, 512);
}

// Round 17
// 129.065 us; speedup vs baseline: 1.1942x; 1.1942x over previous
//
#include <hip/hip_runtime.h>
#include <hip/hip_bf16.h>

#define B_ 2
#define S_ 1024
#define F_ 1024
#define H_ 8
#define D_ 64
#define R_ 2
#define BH (B_*H_)
#define NC 16
#define CL (S_/NC)   // 64

// combined projection layout: [M, NPROJ] fp32
#define QOFF 0
#define KOFF 512
#define VOFF 1536
#define BOFF 2560
#define NPROJ 2624   // 41 * 64
#define M_ (B_*S_)   // 2048

typedef __bf16 bf16x8 __attribute__((ext_vector_type(8)));
typedef unsigned short ushort8 __attribute__((ext_vector_type(8)));
typedef float f32x4 __attribute__((ext_vector_type(4)));

__device__ __forceinline__ unsigned short f2bf(float f) {
    unsigned u = __builtin_bit_cast(unsigned, f);
    unsigned r = u + 0x7FFFu + ((u >> 16) & 1u);
    return (unsigned short)(r >> 16);
}

__device__ __forceinline__ void gload_lds16(const void* g, void* l) {
    __builtin_amdgcn_global_load_lds(
        (const __attribute__((address_space(1))) void*)g,
        (__attribute__((address_space(3))) void*)l, 16, 0, 0);
}

// DPP lane swaps (VALU pipe).
template<int CTRL>
__device__ __forceinline__ float dppf(float x) {
    return __builtin_bit_cast(float, __builtin_amdgcn_update_dpp(
        0, __builtin_bit_cast(int, x), CTRL, 0xF, 0xF, true));
}
__device__ __forceinline__ float qsum8(float x) {
    x += dppf<0xB1>(x);
    x += dppf<0x4E>(x);
    x += dppf<0x141>(x);
    return x;
}

// ------------------------------------------------------------------
// Mask format sniffer + normalize to float 0/1. 8 blocks: each
// redundantly sniffs the format window (deterministic), converts its
// own slice (n/8 = 256 elems = 1/thread).
// ------------------------------------------------------------------
__global__ void k_mask_prep(const void* __restrict__ mraw, float* __restrict__ maskf, int n) {
    __shared__ int fmt; // 0=int32, 1=byte, 2=float32
    int t = threadIdx.x;
    if (t == 0) fmt = 0;
    __syncthreads();
    const unsigned int* u32 = (const unsigned int*)mraw;
    for (int g = t; g < n / 4; g += blockDim.x) {
        unsigned int v = u32[g];
        if (v == 0x3F800000u) atomicMax(&fmt, 2);
        else if (v != 0u && v != 1u) atomicMax(&fmt, 1);
    }
    __syncthreads();
    int f = fmt;
    const unsigned char* u8 = (const unsigned char*)mraw;
    const float* f32 = (const float*)mraw;
    int i = blockIdx.x * (n / 8) + t;
    {
        float mv;
        if (f == 1)      mv = u8[i] ? 1.f : 0.f;
        else if (f == 2) mv = (f32[i] != 0.f) ? 1.f : 0.f;
        else             mv = (u32[i] != 0u) ? 1.f : 0.f;
        maskf[i] = mv;
    }
}

// ------------------------------------------------------------------
// fp32 -> bf16 elementwise (n % 4 == 0)
// ------------------------------------------------------------------
__global__ void k_f32_to_bf16(const float* __restrict__ s, unsigned short* __restrict__ d, int n) {
    int i = (blockIdx.x * blockDim.x + threadIdx.x) * 4;
    if (i < n) {
        float4 v = *(const float4*)&s[i];
        d[i + 0] = f2bf(v.x); d[i + 1] = f2bf(v.y);
        d[i + 2] = f2bf(v.z); d[i + 3] = f2bf(v.w);
    }
}

// ------------------------------------------------------------------
// Pack ALL weights in one kernel. z selects source:
//  0: Wq [1024,512]  -> wt + QOFF*1024
//  1: Wk [1024,1024] -> wt + KOFF*1024
//  2: Wv [1024,1024] -> wt + VOFF*1024
//  3: Wb [1024,16]   -> wt + BOFF*1024 (padded to 64 rows, zeros)
//  4: Wo [512,1024]  -> wo_t
// Each writes dst as [N,K] bf16 (row stride = K).
// ------------------------------------------------------------------
__global__ __launch_bounds__(256) void k_pack_weights(
    const float* __restrict__ Wq, const float* __restrict__ Wk,
    const float* __restrict__ Wv, const float* __restrict__ Wb,
    const float* __restrict__ Wo,
    unsigned short* __restrict__ wt, unsigned short* __restrict__ wo_t)
{
    __shared__ float tile[32][33];
    int z = blockIdx.z;
    const float* src; int kk, nn, padN; unsigned short* dst;
    if (z == 0)      { src = Wq; kk = 1024; nn = 512;  padN = 512;  dst = wt + (size_t)QOFF * 1024; }
    else if (z == 1) { src = Wk; kk = 1024; nn = 1024; padN = 1024; dst = wt + (size_t)KOFF * 1024; }
    else if (z == 2) { src = Wv; kk = 1024; nn = 1024; padN = 1024; dst = wt + (size_t)VOFF * 1024; }
    else if (z == 3) { src = Wb; kk = 1024; nn = 16;   padN = 64;   dst = wt + (size_t)BOFF * 1024; }
    else             { src = Wo; kk = 512;  nn = 1024; padN = 1024; dst = wo_t; }
    int bx = blockIdx.x, by = blockIdx.y;
    if (bx * 32 >= padN || by * 32 >= kk) return;
    int tx = threadIdx.x & 31, ty = threadIdx.x >> 5;
#pragma unroll
    for (int i = 0; i < 32; i += 8) {
        int gr = by * 32 + ty + i, gc = bx * 32 + tx;
        tile[ty + i][tx] = (gc < nn) ? src[(size_t)gr * nn + gc] : 0.f;
    }
    __syncthreads();
#pragma unroll
    for (int i = 0; i < 32; i += 8)
        dst[(size_t)(bx * 32 + ty + i) * kk + by * 32 + tx] = f2bf(tile[tx][ty + i]);
}

// ------------------------------------------------------------------
// bf16 MFMA GEMM: C[M,N] = A[M,K] @ B[K,N] (+bias). Tile 128x64, BK=64.
// ------------------------------------------------------------------
__global__ __launch_bounds__(256) void k_gemm_bf16(
    const unsigned short* __restrict__ A, const unsigned short* __restrict__ Bt,
    const float* __restrict__ bias, float* __restrict__ C,
    int M, int N, int K)
{
    constexpr int BM = 128, BN = 64, BK = 64;
    __shared__ unsigned short sA[BM * BK];
    __shared__ unsigned short sB[BN * BK];
    int t = threadIdx.x;
    int w = t >> 6, l = t & 63;
    int rowb = blockIdx.y * BM, colb = blockIdx.x * BN;
    int wr = w >> 1, wc = w & 1;
    int fr = l & 15, kgrp = l >> 4;

    f32x4 acc[4][2];
#pragma unroll
    for (int m = 0; m < 4; ++m)
#pragma unroll
        for (int n = 0; n < 2; ++n) acc[m][n] = (f32x4){0.f, 0.f, 0.f, 0.f};

    int lrow_off = l >> 3;
    int kg_phys = l & 7;

    for (int k0 = 0; k0 < K; k0 += BK) {
        __syncthreads();
#pragma unroll
        for (int is = 0; is < 4; ++is) {
            int r0 = (w * 4 + is) * 8;
            int row = r0 + lrow_off;
            int kg_log = kg_phys ^ (row & 7);
            gload_lds16(A + (size_t)(rowb + row) * K + k0 + kg_log * 8, &sA[r0 * BK]);
        }
#pragma unroll
        for (int is = 0; is < 2; ++is) {
            int r0 = (w * 2 + is) * 8;
            int row = r0 + lrow_off;
            int kg_log = kg_phys ^ (row & 7);
            gload_lds16(Bt + (size_t)(colb + row) * K + k0 + kg_log * 8, &sB[r0 * BK]);
        }
        asm volatile("s_waitcnt vmcnt(0)" ::: "memory");
        __syncthreads();

#pragma unroll
        for (int kk = 0; kk < BK; kk += 32) {
            int kg = (kk >> 3) + kgrp;
            bf16x8 af[4], bfv[2];
#pragma unroll
            for (int m = 0; m < 4; ++m) {
                int row = wr * 64 + m * 16 + fr;
                ushort8 raw = *(const ushort8*)&sA[row * BK + (kg ^ (row & 7)) * 8];
                af[m] = __builtin_bit_cast(bf16x8, raw);
            }
#pragma unroll
            for (int n = 0; n < 2; ++n) {
                int row = wc * 32 + n * 16 + fr;
                ushort8 raw = *(const ushort8*)&sB[row * BK + (kg ^ (row & 7)) * 8];
                bfv[n] = __builtin_bit_cast(bf16x8, raw);
            }
#pragma unroll
            for (int m = 0; m < 4; ++m)
#pragma unroll
                for (int n = 0; n < 2; ++n)
                    acc[m][n] = __builtin_amdgcn_mfma_f32_16x16x32_bf16(af[m], bfv[n], acc[m][n], 0, 0, 0);
        }
    }

#pragma unroll
    for (int m = 0; m < 4; ++m)
#pragma unroll
        for (int n = 0; n < 2; ++n) {
            int grow0 = rowb + wr * 64 + m * 16 + kgrp * 4;
            int gcol  = colb + wc * 32 + n * 16 + fr;
            float bv = bias ? bias[gcol] : 0.f;
#pragma unroll
            for (int r = 0; r < 4; ++r)
                C[(size_t)(grow0 + r) * N + gcol] = acc[m][n][r] + bv;
        }
}

// ------------------------------------------------------------------
// Fused silu+L2-norm for q (M*8 groups) AND k (M*16 groups), one
// launch. Group g < M*8 -> q-group; else k-group.
// ------------------------------------------------------------------
__global__ void k_silu_norm2(float* __restrict__ buf) {
    int w = threadIdx.x >> 6;
    int l = threadIdx.x & 63;
    int g = blockIdx.x * 4 + w;
    size_t idx;
    if (g < M_ * 8) {
        idx = (size_t)(g >> 3) * NPROJ + QOFF + ((g & 7) << 6) + l;
    } else {
        int g2 = g - M_ * 8;
        idx = (size_t)(g2 >> 4) * NPROJ + KOFF + ((g2 & 15) << 6) + l;
    }
    float x = buf[idx];
    float s = x / (1.f + expf(-x));
    float ss = s * s;
#pragma unroll
    for (int m = 1; m < 64; m <<= 1) ss += __shfl_xor(ss, m);
    float nrm = sqrtf(ss) + 1e-6f;
    buf[idx] = s / nrm;
}

// ------------------------------------------------------------------
// Phase 1 (R12-proven): per (bh, chunk): transfer ops (A_c, B_c) AND
// per-token a_s, b_s (-> ab). 1024 threads: half = A/B state, 8 lanes
// per state row. Flattened double-rank update with precomputed
// token-scalars; DPP 8-lane reduces.
// ------------------------------------------------------------------
__global__ __launch_bounds__(1024) void k_chunk_transfer(
    const float* __restrict__ proj, const float* __restrict__ maskf,
    float* __restrict__ Ac, float* __restrict__ Bc, float* __restrict__ ab)
{
    int c = blockIdx.x;
    int bh = blockIdx.y;
    int b = bh >> 3, h = bh & 7;
    int t = threadIdx.x;
    int half = t >> 9;         // 0 = A-state, 1 = B-state
    int tt = t & 511;
    int i = tt >> 3;           // state row 0..63
    int sub = tt & 7;          // 8-elem slice
    int e0 = sub * 8;
    __shared__ float sK[CL][128];     // 32 KB
    __shared__ float sQ[CL][64];      // 16 KB
    __shared__ float4 sScal[CL];      // {b0, b1, maskscale, -}
    __shared__ float4 sDots[CL];      // {k0.k1, k0.q, k1.q, -}

    size_t tokbase = (size_t)(b * S_ + c * CL);
#pragma unroll
    for (int it = 0; it < (CL * 32) / 1024; ++it) {
        int f = it * 1024 + t;
        int tok = f >> 5, wi = f & 31;
        *(float4*)&sK[tok][wi * 4] = *(const float4*)&proj[(tokbase + tok) * NPROJ + KOFF + h * 128 + wi * 4];
    }
    {
        int f = t;             // CL*16 = 1024 float4, one per thread
        int tok = f >> 4, wi = f & 15;
        *(float4*)&sQ[tok][wi * 4] = *(const float4*)&proj[(tokbase + tok) * NPROJ + QOFF + h * 64 + wi * 4];
    }
    if (t < CL) {
        float r0 = proj[(tokbase + t) * NPROJ + BOFF + h * 2 + 0];
        float r1 = proj[(tokbase + t) * NPROJ + BOFF + h * 2 + 1];
        float ms = 1.f - maskf[tokbase + t];
        sScal[t] = make_float4(1.f / (1.f + expf(-r0)), 1.f / (1.f + expf(-r1)), ms, 0.f);
    }
    __syncthreads();

    // token-scalars: first 512 threads, 8 per token, DPP 8-lane reduce
    if (t < 512) {
        int tok = t >> 3, s8 = (t & 7) * 8;
        float p01 = 0.f, p0q = 0.f, p1q = 0.f;
#pragma unroll
        for (int e = 0; e < 8; ++e) {
            float k0e = sK[tok][s8 + e];
            float k1e = sK[tok][64 + s8 + e];
            float qe  = sQ[tok][s8 + e];
            p01 = fmaf(k0e, k1e, p01);
            p0q = fmaf(k0e, qe,  p0q);
            p1q = fmaf(k1e, qe,  p1q);
        }
        p01 = qsum8(p01); p0q = qsum8(p0q); p1q = qsum8(p1q);
        if ((t & 7) == 0) sDots[tok] = make_float4(p01, p0q, p1q, 0.f);
    }
    __syncthreads();

    float St[8];
#pragma unroll
    for (int j = 0; j < 8; ++j)
        St[j] = (half == 0 && e0 + j == i) ? 1.f : 0.f;

    const float* vbase = &proj[tokbase * NPROJ + VOFF + h * 128];
    float v0 = 0.f, v1 = 0.f;
    if (half) { v0 = vbase[i]; v1 = vbase[64 + i]; }

    float* abdst = ab + ((size_t)bh * NC + c) * (size_t)(CL * 128) + half * 64 + i;

    for (int sl = 0; sl < CL; ++sl) {
        float vc0 = v0, vc1 = v1;
        if (half && sl + 1 < CL) {
            const float* nb = vbase + (size_t)(sl + 1) * NPROJ;
            v0 = nb[i]; v1 = nb[64 + i];
        }
        float4 sc = sScal[sl];
        float4 dt = sDots[sl];
        if (sc.z == 0.f) {           // masked token: state reset (block-uniform, ~5%)
#pragma unroll
            for (int j = 0; j < 8; ++j) St[j] = 0.f;
        }
        float k0[8], k1[8], qq[8];
        *(float4*)&k0[0] = *(const float4*)&sK[sl][e0];
        *(float4*)&k0[4] = *(const float4*)&sK[sl][e0 + 4];
        *(float4*)&k1[0] = *(const float4*)&sK[sl][64 + e0];
        *(float4*)&k1[4] = *(const float4*)&sK[sl][64 + e0 + 4];
        *(float4*)&qq[0] = *(const float4*)&sQ[sl][e0];
        *(float4*)&qq[4] = *(const float4*)&sQ[sl][e0 + 4];
        // 3 independent dots, 2-way split each (6 parallel FMA chains)
        float a0 = 0.f, a1 = 0.f, b0 = 0.f, b1 = 0.f, c0v = 0.f, c1v = 0.f;
#pragma unroll
        for (int q = 0; q < 4; ++q) {
            a0 = fmaf(St[q],     k0[q],     a0);
            a1 = fmaf(St[4 + q], k0[4 + q], a1);
            b0 = fmaf(St[q],     k1[q],     b0);
            b1 = fmaf(St[4 + q], k1[4 + q], b1);
            c0v = fmaf(St[q],     qq[q],     c0v);
            c1v = fmaf(St[4 + q], qq[4 + q], c1v);
        }
        float d0 = qsum8(a0 + a1);
        float d1 = qsum8(b0 + b1);
        float dq = qsum8(c0v + c1v);
        // scalar algebra: both coefs without re-dotting
        float c0, c1;
        if (half == 0) {
            c0 = -sc.x * d0;
            float u1 = fmaf(c0, dt.x, d1);
            c1 = -sc.y * u1;
        } else {
            c0 = sc.x * (vc0 - d0);
            float u1 = fmaf(c0, dt.x, d1);
            c1 = sc.y * (vc1 - u1);
        }
        float xv = fmaf(c1, dt.z, fmaf(c0, dt.y, dq));
        if (sub == 0) abdst[sl * 128] = xv;
#pragma unroll
        for (int j = 0; j < 8; ++j) {
            St[j] = fmaf(c0, k0[j], St[j]);
            St[j] = fmaf(c1, k1[j], St[j]);
        }
    }
    float* dst = (half == 0 ? Ac : Bc) + ((size_t)bh * NC + c) * 4096 + (size_t)i * 64 + e0;
    *(float4*)&dst[0] = make_float4(St[0], St[1], St[2], St[3]);
    *(float4*)&dst[4] = make_float4(St[4], St[5], St[6], St[7]);
}

// ------------------------------------------------------------------
// Phase 2: sequential chunk combine, 64 blocks = 16 bh x 4 row-groups
// of 16 rows, NC=16 steps. Async LDS double-buffer for A; Bc
// register-prefetched one step ahead; padded state rows; separate S0.
// ------------------------------------------------------------------
__global__ __launch_bounds__(256) void k_combine(
    const float* __restrict__ Ac, const float* __restrict__ Bc,
    const float* __restrict__ carry, float* __restrict__ S0,
    float* __restrict__ carry_out)
{
    constexpr int SP = 68;
    int blk = blockIdx.x;
    int bh = blk >> 2, rg = blk & 3;
    int t = threadIdx.x;
    int i = t >> 4;
    int j0 = (t & 15) * 4;
    int gi = rg * 16 + i;
    __shared__ float sA[2][64 * 64];
    __shared__ float sS[16 * SP];

    size_t cb0 = (size_t)bh * NC * 4096;
#pragma unroll
    for (int s = 0; s < 4; ++s)
        gload_lds16(Ac + cb0 + (size_t)(s * 256 + t) * 4, &sA[0][(size_t)(s * 256 + (t & 192)) * 4]);
    float4 rB = *(const float4*)&Bc[cb0 + (size_t)gi * 64 + j0];
    float4 racc = *(const float4*)&carry[(size_t)bh * 4096 + (size_t)gi * 64 + j0];
    *(float4*)&sS[i * SP + j0] = racc;
    asm volatile("s_waitcnt vmcnt(0)" ::: "memory");
    __syncthreads();

    for (int c = 0; c < NC; ++c) {
        int cur = c & 1;
        size_t cb = cb0 + (size_t)c * 4096;
        float4 rBn;
        if (c + 1 < NC) {
#pragma unroll
            for (int s = 0; s < 4; ++s)
                gload_lds16(Ac + cb + 4096 + (size_t)(s * 256 + t) * 4,
                            &sA[cur ^ 1][(size_t)(s * 256 + (t & 192)) * 4]);
            rBn = *(const float4*)&Bc[cb + 4096 + (size_t)gi * 64 + j0];
        }
        *(float4*)&S0[cb + (size_t)gi * 64 + j0] = racc;
        float4 acc = rB;
        float4 ac2 = make_float4(0.f, 0.f, 0.f, 0.f);
#pragma unroll
        for (int p4 = 0; p4 < 16; p4 += 2) {
            float4 s0v = *(const float4*)&sS[i * SP + p4 * 4];
            float4 s1v = *(const float4*)&sS[i * SP + p4 * 4 + 4];
            float4 a0 = *(const float4*)&sA[cur][(p4 * 4 + 0) * 64 + j0];
            float4 a1 = *(const float4*)&sA[cur][(p4 * 4 + 1) * 64 + j0];
            float4 a2 = *(const float4*)&sA[cur][(p4 * 4 + 2) * 64 + j0];
            float4 a3 = *(const float4*)&sA[cur][(p4 * 4 + 3) * 64 + j0];
            float4 a4 = *(const float4*)&sA[cur][(p4 * 4 + 4) * 64 + j0];
            float4 a5 = *(const float4*)&sA[cur][(p4 * 4 + 5) * 64 + j0];
            float4 a6 = *(const float4*)&sA[cur][(p4 * 4 + 6) * 64 + j0];
            float4 a7 = *(const float4*)&sA[cur][(p4 * 4 + 7) * 64 + j0];
            acc.x = fmaf(s0v.x, a0.x, acc.x); acc.y = fmaf(s0v.x, a0.y, acc.y);
            acc.z = fmaf(s0v.x, a0.z, acc.z); acc.w = fmaf(s0v.x, a0.w, acc.w);
            ac2.x = fmaf(s0v.y, a1.x, ac2.x); ac2.y = fmaf(s0v.y, a1.y, ac2.y);
            ac2.z = fmaf(s0v.y, a1.z, ac2.z); ac2.w = fmaf(s0v.y, a1.w, ac2.w);
            acc.x = fmaf(s0v.z, a2.x, acc.x); acc.y = fmaf(s0v.z, a2.y, acc.y);
            acc.z = fmaf(s0v.z, a2.z, acc.z); acc.w = fmaf(s0v.z, a2.w, acc.w);
            ac2.x = fmaf(s0v.w, a3.x, ac2.x); ac2.y = fmaf(s0v.w, a3.y, ac2.y);
            ac2.z = fmaf(s0v.w, a3.z, ac2.z); ac2.w = fmaf(s0v.w, a3.w, ac2.w);
            acc.x = fmaf(s1v.x, a4.x, acc.x); acc.y = fmaf(s1v.x, a4.y, acc.y);
            acc.z = fmaf(s1v.x, a4.z, acc.z); acc.w = fmaf(s1v.x, a4.w, acc.w);
            ac2.x = fmaf(s1v.y, a5.x, ac2.x); ac2.y = fmaf(s1v.y, a5.y, ac2.y);
            ac2.z = fmaf(s1v.y, a5.z, ac2.z); ac2.w = fmaf(s1v.y, a5.w, ac2.w);
            acc.x = fmaf(s1v.z, a6.x, acc.x); acc.y = fmaf(s1v.z, a6.y, acc.y);
            acc.z = fmaf(s1v.z, a6.z, acc.z); acc.w = fmaf(s1v.z, a6.w, acc.w);
            ac2.x = fmaf(s1v.w, a7.x, ac2.x); ac2.y = fmaf(s1v.w, a7.y, ac2.y);
            ac2.z = fmaf(s1v.w, a7.z, ac2.z); ac2.w = fmaf(s1v.w, a7.w, ac2.w);
        }
        acc.x += ac2.x; acc.y += ac2.y; acc.z += ac2.z; acc.w += ac2.w;
        __syncthreads();
        *(float4*)&sS[i * SP + j0] = acc;
        racc = acc;
        rB = rBn;
        asm volatile("s_waitcnt vmcnt(0)" ::: "memory");
        __syncthreads();
    }
    *(float4*)&carry_out[(size_t)bh * 4096 + (size_t)gi * 64 + j0] = racc;
}

// ------------------------------------------------------------------
// Phase 3: X_chunk = Aa @ S0^T + Bb  per (bh, chunk).
// ------------------------------------------------------------------
__global__ __launch_bounds__(256) void k_xgemm(
    const float* __restrict__ ab, const float* __restrict__ S0,
    float* __restrict__ proj)
{
    constexpr int P = 67;
    int c = blockIdx.x, bh = blockIdx.y;
    int b = bh >> 3, h = bh & 7;
    int t = threadIdx.x;
    __shared__ float sAaT[64 * P];   // Aa^T : [p][s]
    __shared__ float sS0T[64 * P];   // S0^T : [p][i]
    size_t abbase = ((size_t)bh * NC + c) * (size_t)(CL * 128);
    size_t s0base = ((size_t)bh * NC + c) * 4096;

#pragma unroll
    for (int it = 0; it < 4; ++it) {
        int f = it * 256 + t;
        int r = f >> 4, p0 = (f & 15) * 4;
        float4 va = *(const float4*)&ab[abbase + (size_t)r * 128 + p0];
        sAaT[(p0 + 0) * P + r] = va.x; sAaT[(p0 + 1) * P + r] = va.y;
        sAaT[(p0 + 2) * P + r] = va.z; sAaT[(p0 + 3) * P + r] = va.w;
        float4 vs = *(const float4*)&S0[s0base + (size_t)r * 64 + p0];
        sS0T[(p0 + 0) * P + r] = vs.x; sS0T[(p0 + 1) * P + r] = vs.y;
        sS0T[(p0 + 2) * P + r] = vs.z; sS0T[(p0 + 3) * P + r] = vs.w;
    }
    __syncthreads();

    int s0r = (t >> 4) * 4;
    int i0 = (t & 15) * 4;
    size_t tokbase = (size_t)(b * S_ + c * CL);
    float4 acc[4];
#pragma unroll
    for (int a = 0; a < 4; ++a)
        acc[a] = *(const float4*)&ab[abbase + (size_t)(s0r + a) * 128 + 64 + i0];
#pragma unroll 8
    for (int p = 0; p < 64; ++p) {
        float4 aa = *(const float4*)&sAaT[p * P + s0r];
        float4 ss = *(const float4*)&sS0T[p * P + i0];
        acc[0].x = fmaf(aa.x, ss.x, acc[0].x); acc[0].y = fmaf(aa.x, ss.y, acc[0].y);
        acc[0].z = fmaf(aa.x, ss.z, acc[0].z); acc[0].w = fmaf(aa.x, ss.w, acc[0].w);
        acc[1].x = fmaf(aa.y, ss.x, acc[1].x); acc[1].y = fmaf(aa.y, ss.y, acc[1].y);
        acc[1].z = fmaf(aa.y, ss.z, acc[1].z); acc[1].w = fmaf(aa.y, ss.w, acc[1].w);
        acc[2].x = fmaf(aa.z, ss.x, acc[2].x); acc[2].y = fmaf(aa.z, ss.y, acc[2].y);
        acc[2].z = fmaf(aa.z, ss.z, acc[2].z); acc[2].w = fmaf(aa.z, ss.w, acc[2].w);
        acc[3].x = fmaf(aa.w, ss.x, acc[3].x); acc[3].y = fmaf(aa.w, ss.y, acc[3].y);
        acc[3].z = fmaf(aa.w, ss.z, acc[3].z); acc[3].w = fmaf(aa.w, ss.w, acc[3].w);
    }
#pragma unroll
    for (int a = 0; a < 4; ++a)
        *(float4*)&proj[(tokbase + s0r + a) * NPROJ + QOFF + h * 64 + i0] = acc[a];
}

// ------------------------------------------------------------------
// RMS norm over x = proj cols 0..511, * rms_scale, emit compact bf16.
// ------------------------------------------------------------------
__global__ void k_rms_bf16(const float* __restrict__ proj, const float* __restrict__ scale,
                           unsigned short* __restrict__ xo) {
    int w = threadIdx.x >> 6;
    int l = threadIdx.x & 63;
    size_t row = (size_t)blockIdx.x * 4 + w;
    float4 v0 = *(const float4*)&proj[row * NPROJ + l * 8];
    float4 v1 = *(const float4*)&proj[row * NPROJ + l * 8 + 4];
    float ss = v0.x * v0.x + v0.y * v0.y + v0.z * v0.z + v0.w * v0.w
             + v1.x * v1.x + v1.y * v1.y + v1.z * v1.z + v1.w * v1.w;
#pragma unroll
    for (int m = 1; m < 64; m <<= 1) ss += __shfl_xor(ss, m);
    float sc = rsqrtf(ss * (1.f / 512.f) + 1e-6f);
    float4 s0 = *(const float4*)&scale[l * 8];
    float4 s1 = *(const float4*)&scale[l * 8 + 4];
    ushort8 o;
    o[0] = f2bf(v0.x * sc * s0.x); o[1] = f2bf(v0.y * sc * s0.y);
    o[2] = f2bf(v0.z * sc * s0.z); o[3] = f2bf(v0.w * sc * s0.w);
    o[4] = f2bf(v1.x * sc * s1.x); o[5] = f2bf(v1.y * sc * s1.y);
    o[6] = f2bf(v1.z * sc * s1.z); o[7] = f2bf(v1.w * sc * s1.w);
    *(ushort8*)&xo[row * 512 + l * 8] = o;
}

// ------------------------------------------------------------------
extern "C" void kernel_launch(void* const* d_in, const int* in_sizes, int n_in,
                              void* d_out, int out_size, void* d_ws, size_t ws_size,
                              hipStream_t stream) {
    const float* inputs    = (const float*)d_in[0];
    const void*  mask      = d_in[1];
    const float* carry     = (const float*)d_in[2];
    const float* Wq        = (const float*)d_in[3];
    const float* Wk        = (const float*)d_in[4];
    const float* Wv        = (const float*)d_in[5];
    const float* Wb        = (const float*)d_in[6];
    const float* rms_scale = (const float*)d_in[7];
    const float* Wo        = (const float*)d_in[8];
    const float* bo        = (const float*)d_in[9];

    float* out_carry = (float*)d_out;
    float* out_y     = (float*)d_out + (size_t)B_ * H_ * D_ * D_;

    const int M = M_;  // 2048
    float* ws = (float*)d_ws;
    size_t o = 0;
    float* proj = ws + o; o += (size_t)M * NPROJ;            // 5.37M f
    float* mf   = ws + o; o += (size_t)M;
    float* Ac   = ws + o; o += (size_t)BH * NC * 4096;       // 1M f
    float* Bc   = ws + o; o += (size_t)BH * NC * 4096;       // 1M f
    float* S0   = ws + o; o += (size_t)BH * NC * 4096;       // 1M f
    float* abuf = ws + o; o += (size_t)BH * NC * CL * 128;   // 2M f
    unsigned short* wt   = (unsigned short*)(ws + o); o += (size_t)NPROJ * 512;   // bf16 [NPROJ,1024]
    unsigned short* wo_t = (unsigned short*)(ws + o); o += (size_t)1024 * 256;    // bf16 [1024,512]
    // overlays (lifetimes disjoint):
    unsigned short* inb = (unsigned short*)Bc;   // bf16 inputs, dead before transfer writes Bc
    unsigned short* xbf = (unsigned short*)Ac;   // rms output; Ac dead after combine

    k_mask_prep<<<8, 256, 0, stream>>>(mask, mf, M);
    k_f32_to_bf16<<<(M * 1024) / 1024, 256, 0, stream>>>(inputs, inb, M * 1024);

    // pack all weights (Wq/Wk/Wv/Wb -> wt, Wo -> wo_t) in ONE launch
    k_pack_weights<<<dim3(32, 32, 5), 256, 0, stream>>>(Wq, Wk, Wv, Wb, Wo, wt, wo_t);

    // proj = inputs @ [Wq|Wk|Wv|Wb]
    k_gemm_bf16<<<dim3(NPROJ / 64, M / 128), 256, 0, stream>>>(inb, wt, nullptr, proj, M, NPROJ, 1024);

    // silu+L2norm on q and k, one launch (M*24 groups)
    k_silu_norm2<<<(M * 24) / 4, 256, 0, stream>>>(proj);

    // scan: transfer (+ per-token a,b vectors) -> combine -> X = Aa@S0^T + Bb
    k_chunk_transfer<<<dim3(NC, BH), 1024, 0, stream>>>(proj, mf, Ac, Bc, abuf);
    k_combine<<<BH * 4, 256, 0, stream>>>(Ac, Bc, carry, S0, out_carry);
    k_xgemm<<<dim3(NC, BH), 256, 0, stream>>>(abuf, S0, proj);

    k_rms_bf16<<<M / 4, 256, 0, stream>>>(proj, rms_scale, xbf);

    // y = x @ Wo + bo  (K=512, N=1024)
    k_gemm_bf16<<<dim3(1024 / 64, M / 128), 256, 0, stream>>>(xbf, wo_t, bo, out_y, M, 1024, 512);
}

// Round 19
// 128.825 us; speedup vs baseline: 1.1964x; 1.0019x over previous
//
#include <hip/hip_runtime.h>
#include <hip/hip_bf16.h>

#define B_ 2
#define S_ 1024
#define F_ 1024
#define H_ 8
#define D_ 64
#define R_ 2
#define BH (B_*H_)
#define NC 16
#define CL (S_/NC)   // 64

// combined projection layout: [M, NPROJ] fp32
#define QOFF 0
#define KOFF 512
#define VOFF 1536
#define BOFF 2560
#define NPROJ 2624   // 41 * 64
#define M_ (B_*S_)   // 2048

typedef __bf16 bf16x8 __attribute__((ext_vector_type(8)));
typedef unsigned short ushort8 __attribute__((ext_vector_type(8)));
typedef float f32x4 __attribute__((ext_vector_type(4)));

__device__ __forceinline__ unsigned short f2bf(float f) {
    unsigned u = __builtin_bit_cast(unsigned, f);
    unsigned r = u + 0x7FFFu + ((u >> 16) & 1u);
    return (unsigned short)(r >> 16);
}

__device__ __forceinline__ void gload_lds16(const void* g, void* l) {
    __builtin_amdgcn_global_load_lds(
        (const __attribute__((address_space(1))) void*)g,
        (__attribute__((address_space(3))) void*)l, 16, 0, 0);
}

// DPP lane swaps (VALU pipe).
template<int CTRL>
__device__ __forceinline__ float dppf(float x) {
    return __builtin_bit_cast(float, __builtin_amdgcn_update_dpp(
        0, __builtin_bit_cast(int, x), CTRL, 0xF, 0xF, true));
}
__device__ __forceinline__ float qsum8(float x) {
    x += dppf<0xB1>(x);
    x += dppf<0x4E>(x);
    x += dppf<0x141>(x);
    return x;
}

// ------------------------------------------------------------------
// Mask format sniffer + normalize to float 0/1. 8 blocks: each
// redundantly sniffs the format window (deterministic), converts its
// own slice (n/8 = 256 elems = 1/thread).
// ------------------------------------------------------------------
__global__ void k_mask_prep(const void* __restrict__ mraw, float* __restrict__ maskf, int n) {
    __shared__ int fmt; // 0=int32, 1=byte, 2=float32
    int t = threadIdx.x;
    if (t == 0) fmt = 0;
    __syncthreads();
    const unsigned int* u32 = (const unsigned int*)mraw;
    for (int g = t; g < n / 4; g += blockDim.x) {
        unsigned int v = u32[g];
        if (v == 0x3F800000u) atomicMax(&fmt, 2);
        else if (v != 0u && v != 1u) atomicMax(&fmt, 1);
    }
    __syncthreads();
    int f = fmt;
    const unsigned char* u8 = (const unsigned char*)mraw;
    const float* f32 = (const float*)mraw;
    int i = blockIdx.x * (n / 8) + t;
    {
        float mv;
        if (f == 1)      mv = u8[i] ? 1.f : 0.f;
        else if (f == 2) mv = (f32[i] != 0.f) ? 1.f : 0.f;
        else             mv = (u32[i] != 0u) ? 1.f : 0.f;
        maskf[i] = mv;
    }
}

// ------------------------------------------------------------------
// fp32 -> bf16 elementwise (n % 4 == 0)
// ------------------------------------------------------------------
__global__ void k_f32_to_bf16(const float* __restrict__ s, unsigned short* __restrict__ d, int n) {
    int i = (blockIdx.x * blockDim.x + threadIdx.x) * 4;
    if (i < n) {
        float4 v = *(const float4*)&s[i];
        d[i + 0] = f2bf(v.x); d[i + 1] = f2bf(v.y);
        d[i + 2] = f2bf(v.z); d[i + 3] = f2bf(v.w);
    }
}

// ------------------------------------------------------------------
// Pack ALL weights in one kernel. z selects source:
//  0: Wq [1024,512]  -> wt + QOFF*1024
//  1: Wk [1024,1024] -> wt + KOFF*1024
//  2: Wv [1024,1024] -> wt + VOFF*1024
//  3: Wb [1024,16]   -> wt + BOFF*1024 (padded to 64 rows, zeros)
//  4: Wo [512,1024]  -> wo_t
// Each writes dst as [N,K] bf16 (row stride = K).
// ------------------------------------------------------------------
__global__ __launch_bounds__(256) void k_pack_weights(
    const float* __restrict__ Wq, const float* __restrict__ Wk,
    const float* __restrict__ Wv, const float* __restrict__ Wb,
    const float* __restrict__ Wo,
    unsigned short* __restrict__ wt, unsigned short* __restrict__ wo_t)
{
    __shared__ float tile[32][33];
    int z = blockIdx.z;
    const float* src; int kk, nn, padN; unsigned short* dst;
    if (z == 0)      { src = Wq; kk = 1024; nn = 512;  padN = 512;  dst = wt + (size_t)QOFF * 1024; }
    else if (z == 1) { src = Wk; kk = 1024; nn = 1024; padN = 1024; dst = wt + (size_t)KOFF * 1024; }
    else if (z == 2) { src = Wv; kk = 1024; nn = 1024; padN = 1024; dst = wt + (size_t)VOFF * 1024; }
    else if (z == 3) { src = Wb; kk = 1024; nn = 16;   padN = 64;   dst = wt + (size_t)BOFF * 1024; }
    else             { src = Wo; kk = 512;  nn = 1024; padN = 1024; dst = wo_t; }
    int bx = blockIdx.x, by = blockIdx.y;
    if (bx * 32 >= padN || by * 32 >= kk) return;
    int tx = threadIdx.x & 31, ty = threadIdx.x >> 5;
#pragma unroll
    for (int i = 0; i < 32; i += 8) {
        int gr = by * 32 + ty + i, gc = bx * 32 + tx;
        tile[ty + i][tx] = (gc < nn) ? src[(size_t)gr * nn + gc] : 0.f;
    }
    __syncthreads();
#pragma unroll
    for (int i = 0; i < 32; i += 8)
        dst[(size_t)(bx * 32 + ty + i) * kk + by * 32 + tx] = f2bf(tile[tx][ty + i]);
}

// ------------------------------------------------------------------
// bf16 MFMA GEMM: C[M,N] = A[M,K] @ B[K,N] (+bias). Tile 128x64, BK=64.
// ------------------------------------------------------------------
__global__ __launch_bounds__(256) void k_gemm_bf16(
    const unsigned short* __restrict__ A, const unsigned short* __restrict__ Bt,
    const float* __restrict__ bias, float* __restrict__ C,
    int M, int N, int K)
{
    constexpr int BM = 128, BN = 64, BK = 64;
    __shared__ unsigned short sA[BM * BK];
    __shared__ unsigned short sB[BN * BK];
    int t = threadIdx.x;
    int w = t >> 6, l = t & 63;
    int rowb = blockIdx.y * BM, colb = blockIdx.x * BN;
    int wr = w >> 1, wc = w & 1;
    int fr = l & 15, kgrp = l >> 4;

    f32x4 acc[4][2];
#pragma unroll
    for (int m = 0; m < 4; ++m)
#pragma unroll
        for (int n = 0; n < 2; ++n) acc[m][n] = (f32x4){0.f, 0.f, 0.f, 0.f};

    int lrow_off = l >> 3;
    int kg_phys = l & 7;

    for (int k0 = 0; k0 < K; k0 += BK) {
        __syncthreads();
#pragma unroll
        for (int is = 0; is < 4; ++is) {
            int r0 = (w * 4 + is) * 8;
            int row = r0 + lrow_off;
            int kg_log = kg_phys ^ (row & 7);
            gload_lds16(A + (size_t)(rowb + row) * K + k0 + kg_log * 8, &sA[r0 * BK]);
        }
#pragma unroll
        for (int is = 0; is < 2; ++is) {
            int r0 = (w * 2 + is) * 8;
            int row = r0 + lrow_off;
            int kg_log = kg_phys ^ (row & 7);
            gload_lds16(Bt + (size_t)(colb + row) * K + k0 + kg_log * 8, &sB[r0 * BK]);
        }
        asm volatile("s_waitcnt vmcnt(0)" ::: "memory");
        __syncthreads();

#pragma unroll
        for (int kk = 0; kk < BK; kk += 32) {
            int kg = (kk >> 3) + kgrp;
            bf16x8 af[4], bfv[2];
#pragma unroll
            for (int m = 0; m < 4; ++m) {
                int row = wr * 64 + m * 16 + fr;
                ushort8 raw = *(const ushort8*)&sA[row * BK + (kg ^ (row & 7)) * 8];
                af[m] = __builtin_bit_cast(bf16x8, raw);
            }
#pragma unroll
            for (int n = 0; n < 2; ++n) {
                int row = wc * 32 + n * 16 + fr;
                ushort8 raw = *(const ushort8*)&sB[row * BK + (kg ^ (row & 7)) * 8];
                bfv[n] = __builtin_bit_cast(bf16x8, raw);
            }
#pragma unroll
            for (int m = 0; m < 4; ++m)
#pragma unroll
                for (int n = 0; n < 2; ++n)
                    acc[m][n] = __builtin_amdgcn_mfma_f32_16x16x32_bf16(af[m], bfv[n], acc[m][n], 0, 0, 0);
        }
    }

#pragma unroll
    for (int m = 0; m < 4; ++m)
#pragma unroll
        for (int n = 0; n < 2; ++n) {
            int grow0 = rowb + wr * 64 + m * 16 + kgrp * 4;
            int gcol  = colb + wc * 32 + n * 16 + fr;
            float bv = bias ? bias[gcol] : 0.f;
#pragma unroll
            for (int r = 0; r < 4; ++r)
                C[(size_t)(grow0 + r) * N + gcol] = acc[m][n][r] + bv;
        }
}

// ------------------------------------------------------------------
// Fused silu+L2-norm for q (M*8 groups) AND k (M*16 groups), one
// launch. Group g < M*8 -> q-group; else k-group.
// ------------------------------------------------------------------
__global__ void k_silu_norm2(float* __restrict__ buf) {
    int w = threadIdx.x >> 6;
    int l = threadIdx.x & 63;
    int g = blockIdx.x * 4 + w;
    size_t idx;
    if (g < M_ * 8) {
        idx = (size_t)(g >> 3) * NPROJ + QOFF + ((g & 7) << 6) + l;
    } else {
        int g2 = g - M_ * 8;
        idx = (size_t)(g2 >> 4) * NPROJ + KOFF + ((g2 & 15) << 6) + l;
    }
    float x = buf[idx];
    float s = x / (1.f + expf(-x));
    float ss = s * s;
#pragma unroll
    for (int m = 1; m < 64; m <<= 1) ss += __shfl_xor(ss, m);
    float nrm = sqrtf(ss) + 1e-6f;
    buf[idx] = s / nrm;
}

// ------------------------------------------------------------------
// Phase 1 (R12-proven): per (bh, chunk): transfer ops (A_c, B_c) AND
// per-token a_s, b_s (-> ab). 1024 threads: half = A/B state, 8 lanes
// per state row. Flattened double-rank update with precomputed
// token-scalars; DPP 8-lane reduces.
// ------------------------------------------------------------------
__global__ __launch_bounds__(1024) void k_chunk_transfer(
    const float* __restrict__ proj, const float* __restrict__ maskf,
    float* __restrict__ Ac, float* __restrict__ Bc, float* __restrict__ ab)
{
    int c = blockIdx.x;
    int bh = blockIdx.y;
    int b = bh >> 3, h = bh & 7;
    int t = threadIdx.x;
    int half = t >> 9;         // 0 = A-state, 1 = B-state
    int tt = t & 511;
    int i = tt >> 3;           // state row 0..63
    int sub = tt & 7;          // 8-elem slice
    int e0 = sub * 8;
    __shared__ float sK[CL][128];     // 32 KB
    __shared__ float sQ[CL][64];      // 16 KB
    __shared__ float4 sScal[CL];      // {b0, b1, maskscale, -}
    __shared__ float4 sDots[CL];      // {k0.k1, k0.q, k1.q, -}

    size_t tokbase = (size_t)(b * S_ + c * CL);
#pragma unroll
    for (int it = 0; it < (CL * 32) / 1024; ++it) {
        int f = it * 1024 + t;
        int tok = f >> 5, wi = f & 31;
        *(float4*)&sK[tok][wi * 4] = *(const float4*)&proj[(tokbase + tok) * NPROJ + KOFF + h * 128 + wi * 4];
    }
    {
        int f = t;             // CL*16 = 1024 float4, one per thread
        int tok = f >> 4, wi = f & 15;
        *(float4*)&sQ[tok][wi * 4] = *(const float4*)&proj[(tokbase + tok) * NPROJ + QOFF + h * 64 + wi * 4];
    }
    if (t < CL) {
        float r0 = proj[(tokbase + t) * NPROJ + BOFF + h * 2 + 0];
        float r1 = proj[(tokbase + t) * NPROJ + BOFF + h * 2 + 1];
        float ms = 1.f - maskf[tokbase + t];
        sScal[t] = make_float4(1.f / (1.f + expf(-r0)), 1.f / (1.f + expf(-r1)), ms, 0.f);
    }
    __syncthreads();

    // token-scalars: first 512 threads, 8 per token, DPP 8-lane reduce
    if (t < 512) {
        int tok = t >> 3, s8 = (t & 7) * 8;
        float p01 = 0.f, p0q = 0.f, p1q = 0.f;
#pragma unroll
        for (int e = 0; e < 8; ++e) {
            float k0e = sK[tok][s8 + e];
            float k1e = sK[tok][64 + s8 + e];
            float qe  = sQ[tok][s8 + e];
            p01 = fmaf(k0e, k1e, p01);
            p0q = fmaf(k0e, qe,  p0q);
            p1q = fmaf(k1e, qe,  p1q);
        }
        p01 = qsum8(p01); p0q = qsum8(p0q); p1q = qsum8(p1q);
        if ((t & 7) == 0) sDots[tok] = make_float4(p01, p0q, p1q, 0.f);
    }
    __syncthreads();

    float St[8];
#pragma unroll
    for (int j = 0; j < 8; ++j)
        St[j] = (half == 0 && e0 + j == i) ? 1.f : 0.f;

    const float* vbase = &proj[tokbase * NPROJ + VOFF + h * 128];
    float v0 = 0.f, v1 = 0.f;
    if (half) { v0 = vbase[i]; v1 = vbase[64 + i]; }

    float* abdst = ab + ((size_t)bh * NC + c) * (size_t)(CL * 128) + half * 64 + i;

    for (int sl = 0; sl < CL; ++sl) {
        float vc0 = v0, vc1 = v1;
        if (half && sl + 1 < CL) {
            const float* nb = vbase + (size_t)(sl + 1) * NPROJ;
            v0 = nb[i]; v1 = nb[64 + i];
        }
        float4 sc = sScal[sl];
        float4 dt = sDots[sl];
        if (sc.z == 0.f) {           // masked token: state reset (block-uniform, ~5%)
#pragma unroll
            for (int j = 0; j < 8; ++j) St[j] = 0.f;
        }
        float k0[8], k1[8], qq[8];
        *(float4*)&k0[0] = *(const float4*)&sK[sl][e0];
        *(float4*)&k0[4] = *(const float4*)&sK[sl][e0 + 4];
        *(float4*)&k1[0] = *(const float4*)&sK[sl][64 + e0];
        *(float4*)&k1[4] = *(const float4*)&sK[sl][64 + e0 + 4];
        *(float4*)&qq[0] = *(const float4*)&sQ[sl][e0];
        *(float4*)&qq[4] = *(const float4*)&sQ[sl][e0 + 4];
        // 3 independent dots, 2-way split each (6 parallel FMA chains)
        float a0 = 0.f, a1 = 0.f, b0 = 0.f, b1 = 0.f, c0v = 0.f, c1v = 0.f;
#pragma unroll
        for (int q = 0; q < 4; ++q) {
            a0 = fmaf(St[q],     k0[q],     a0);
            a1 = fmaf(St[4 + q], k0[4 + q], a1);
            b0 = fmaf(St[q],     k1[q],     b0);
            b1 = fmaf(St[4 + q], k1[4 + q], b1);
            c0v = fmaf(St[q],     qq[q],     c0v);
            c1v = fmaf(St[4 + q], qq[4 + q], c1v);
        }
        float d0 = qsum8(a0 + a1);
        float d1 = qsum8(b0 + b1);
        float dq = qsum8(c0v + c1v);
        // scalar algebra: both coefs without re-dotting
        float c0, c1;
        if (half == 0) {
            c0 = -sc.x * d0;
            float u1 = fmaf(c0, dt.x, d1);
            c1 = -sc.y * u1;
        } else {
            c0 = sc.x * (vc0 - d0);
            float u1 = fmaf(c0, dt.x, d1);
            c1 = sc.y * (vc1 - u1);
        }
        float xv = fmaf(c1, dt.z, fmaf(c0, dt.y, dq));
        if (sub == 0) abdst[sl * 128] = xv;
#pragma unroll
        for (int j = 0; j < 8; ++j) {
            St[j] = fmaf(c0, k0[j], St[j]);
            St[j] = fmaf(c1, k1[j], St[j]);
        }
    }
    float* dst = (half == 0 ? Ac : Bc) + ((size_t)bh * NC + c) * 4096 + (size_t)i * 64 + e0;
    *(float4*)&dst[0] = make_float4(St[0], St[1], St[2], St[3]);
    *(float4*)&dst[4] = make_float4(St[4], St[5], St[6], St[7]);
}

// ------------------------------------------------------------------
// Phase 2: sequential chunk combine, 64 blocks = 16 bh x 4 row-groups
// of 16 rows, NC=16 steps. Async LDS double-buffer for A; Bc
// register-prefetched one step ahead; padded state rows; separate S0.
// ------------------------------------------------------------------
__global__ __launch_bounds__(256) void k_combine(
    const float* __restrict__ Ac, const float* __restrict__ Bc,
    const float* __restrict__ carry, float* __restrict__ S0,
    float* __restrict__ carry_out)
{
    constexpr int SP = 68;
    int blk = blockIdx.x;
    int bh = blk >> 2, rg = blk & 3;
    int t = threadIdx.x;
    int i = t >> 4;
    int j0 = (t & 15) * 4;
    int gi = rg * 16 + i;
    __shared__ float sA[2][64 * 64];
    __shared__ float sS[16 * SP];

    size_t cb0 = (size_t)bh * NC * 4096;
#pragma unroll
    for (int s = 0; s < 4; ++s)
        gload_lds16(Ac + cb0 + (size_t)(s * 256 + t) * 4, &sA[0][(size_t)(s * 256 + (t & 192)) * 4]);
    float4 rB = *(const float4*)&Bc[cb0 + (size_t)gi * 64 + j0];
    float4 racc = *(const float4*)&carry[(size_t)bh * 4096 + (size_t)gi * 64 + j0];
    *(float4*)&sS[i * SP + j0] = racc;
    asm volatile("s_waitcnt vmcnt(0)" ::: "memory");
    __syncthreads();

    for (int c = 0; c < NC; ++c) {
        int cur = c & 1;
        size_t cb = cb0 + (size_t)c * 4096;
        float4 rBn;
        if (c + 1 < NC) {
#pragma unroll
            for (int s = 0; s < 4; ++s)
                gload_lds16(Ac + cb + 4096 + (size_t)(s * 256 + t) * 4,
                            &sA[cur ^ 1][(size_t)(s * 256 + (t & 192)) * 4]);
            rBn = *(const float4*)&Bc[cb + 4096 + (size_t)gi * 64 + j0];
        }
        *(float4*)&S0[cb + (size_t)gi * 64 + j0] = racc;
        float4 acc = rB;
        float4 ac2 = make_float4(0.f, 0.f, 0.f, 0.f);
#pragma unroll
        for (int p4 = 0; p4 < 16; p4 += 2) {
            float4 s0v = *(const float4*)&sS[i * SP + p4 * 4];
            float4 s1v = *(const float4*)&sS[i * SP + p4 * 4 + 4];
            float4 a0 = *(const float4*)&sA[cur][(p4 * 4 + 0) * 64 + j0];
            float4 a1 = *(const float4*)&sA[cur][(p4 * 4 + 1) * 64 + j0];
            float4 a2 = *(const float4*)&sA[cur][(p4 * 4 + 2) * 64 + j0];
            float4 a3 = *(const float4*)&sA[cur][(p4 * 4 + 3) * 64 + j0];
            float4 a4 = *(const float4*)&sA[cur][(p4 * 4 + 4) * 64 + j0];
            float4 a5 = *(const float4*)&sA[cur][(p4 * 4 + 5) * 64 + j0];
            float4 a6 = *(const float4*)&sA[cur][(p4 * 4 + 6) * 64 + j0];
            float4 a7 = *(const float4*)&sA[cur][(p4 * 4 + 7) * 64 + j0];
            acc.x = fmaf(s0v.x, a0.x, acc.x); acc.y = fmaf(s0v.x, a0.y, acc.y);
            acc.z = fmaf(s0v.x, a0.z, acc.z); acc.w = fmaf(s0v.x, a0.w, acc.w);
            ac2.x = fmaf(s0v.y, a1.x, ac2.x); ac2.y = fmaf(s0v.y, a1.y, ac2.y);
            ac2.z = fmaf(s0v.y, a1.z, ac2.z); ac2.w = fmaf(s0v.y, a1.w, ac2.w);
            acc.x = fmaf(s0v.z, a2.x, acc.x); acc.y = fmaf(s0v.z, a2.y, acc.y);
            acc.z = fmaf(s0v.z, a2.z, acc.z); acc.w = fmaf(s0v.z, a2.w, acc.w);
            ac2.x = fmaf(s0v.w, a3.x, ac2.x); ac2.y = fmaf(s0v.w, a3.y, ac2.y);
            ac2.z = fmaf(s0v.w, a3.z, ac2.z); ac2.w = fmaf(s0v.w, a3.w, ac2.w);
            acc.x = fmaf(s1v.x, a4.x, acc.x); acc.y = fmaf(s1v.x, a4.y, acc.y);
            acc.z = fmaf(s1v.x, a4.z, acc.z); acc.w = fmaf(s1v.x, a4.w, acc.w);
            ac2.x = fmaf(s1v.y, a5.x, ac2.x); ac2.y = fmaf(s1v.y, a5.y, ac2.y);
            ac2.z = fmaf(s1v.y, a5.z, ac2.z); ac2.w = fmaf(s1v.y, a5.w, ac2.w);
            acc.x = fmaf(s1v.z, a6.x, acc.x); acc.y = fmaf(s1v.z, a6.y, acc.y);
            acc.z = fmaf(s1v.z, a6.z, acc.z); acc.w = fmaf(s1v.z, a6.w, acc.w);
            ac2.x = fmaf(s1v.w, a7.x, ac2.x); ac2.y = fmaf(s1v.w, a7.y, ac2.y);
            ac2.z = fmaf(s1v.w, a7.z, ac2.z); ac2.w = fmaf(s1v.w, a7.w, ac2.w);
        }
        acc.x += ac2.x; acc.y += ac2.y; acc.z += ac2.z; acc.w += ac2.w;
        __syncthreads();
        *(float4*)&sS[i * SP + j0] = acc;
        racc = acc;
        rB = rBn;
        asm volatile("s_waitcnt vmcnt(0)" ::: "memory");
        __syncthreads();
    }
    *(float4*)&carry_out[(size_t)bh * 4096 + (size_t)gi * 64 + j0] = racc;
}

// ------------------------------------------------------------------
// Phase 3: X_chunk = Aa @ S0^T + Bb  per (bh, chunk).
// ------------------------------------------------------------------
__global__ __launch_bounds__(256) void k_xgemm(
    const float* __restrict__ ab, const float* __restrict__ S0,
    float* __restrict__ proj)
{
    constexpr int P = 67;
    int c = blockIdx.x, bh = blockIdx.y;
    int b = bh >> 3, h = bh & 7;
    int t = threadIdx.x;
    __shared__ float sAaT[64 * P];   // Aa^T : [p][s]
    __shared__ float sS0T[64 * P];   // S0^T : [p][i]
    size_t abbase = ((size_t)bh * NC + c) * (size_t)(CL * 128);
    size_t s0base = ((size_t)bh * NC + c) * 4096;

#pragma unroll
    for (int it = 0; it < 4; ++it) {
        int f = it * 256 + t;
        int r = f >> 4, p0 = (f & 15) * 4;
        float4 va = *(const float4*)&ab[abbase + (size_t)r * 128 + p0];
        sAaT[(p0 + 0) * P + r] = va.x; sAaT[(p0 + 1) * P + r] = va.y;
        sAaT[(p0 + 2) * P + r] = va.z; sAaT[(p0 + 3) * P + r] = va.w;
        float4 vs = *(const float4*)&S0[s0base + (size_t)r * 64 + p0];
        sS0T[(p0 + 0) * P + r] = vs.x; sS0T[(p0 + 1) * P + r] = vs.y;
        sS0T[(p0 + 2) * P + r] = vs.z; sS0T[(p0 + 3) * P + r] = vs.w;
    }
    __syncthreads();

    int s0r = (t >> 4) * 4;
    int i0 = (t & 15) * 4;
    size_t tokbase = (size_t)(b * S_ + c * CL);
    float4 acc[4];
#pragma unroll
    for (int a = 0; a < 4; ++a)
        acc[a] = *(const float4*)&ab[abbase + (size_t)(s0r + a) * 128 + 64 + i0];
#pragma unroll 8
    for (int p = 0; p < 64; ++p) {
        float4 aa = *(const float4*)&sAaT[p * P + s0r];
        float4 ss = *(const float4*)&sS0T[p * P + i0];
        acc[0].x = fmaf(aa.x, ss.x, acc[0].x); acc[0].y = fmaf(aa.x, ss.y, acc[0].y);
        acc[0].z = fmaf(aa.x, ss.z, acc[0].z); acc[0].w = fmaf(aa.x, ss.w, acc[0].w);
        acc[1].x = fmaf(aa.y, ss.x, acc[1].x); acc[1].y = fmaf(aa.y, ss.y, acc[1].y);
        acc[1].z = fmaf(aa.y, ss.z, acc[1].z); acc[1].w = fmaf(aa.y, ss.w, acc[1].w);
        acc[2].x = fmaf(aa.z, ss.x, acc[2].x); acc[2].y = fmaf(aa.z, ss.y, acc[2].y);
        acc[2].z = fmaf(aa.z, ss.z, acc[2].z); acc[2].w = fmaf(aa.z, ss.w, acc[2].w);
        acc[3].x = fmaf(aa.w, ss.x, acc[3].x); acc[3].y = fmaf(aa.w, ss.y, acc[3].y);
        acc[3].z = fmaf(aa.w, ss.z, acc[3].z); acc[3].w = fmaf(aa.w, ss.w, acc[3].w);
    }
#pragma unroll
    for (int a = 0; a < 4; ++a)
        *(float4*)&proj[(tokbase + s0r + a) * NPROJ + QOFF + h * 64 + i0] = acc[a];
}

// ------------------------------------------------------------------
// RMS norm over x = proj cols 0..511, * rms_scale, emit compact bf16.
// ------------------------------------------------------------------
__global__ void k_rms_bf16(const float* __restrict__ proj, const float* __restrict__ scale,
                           unsigned short* __restrict__ xo) {
    int w = threadIdx.x >> 6;
    int l = threadIdx.x & 63;
    size_t row = (size_t)blockIdx.x * 4 + w;
    float4 v0 = *(const float4*)&proj[row * NPROJ + l * 8];
    float4 v1 = *(const float4*)&proj[row * NPROJ + l * 8 + 4];
    float ss = v0.x * v0.x + v0.y * v0.y + v0.z * v0.z + v0.w * v0.w
             + v1.x * v1.x + v1.y * v1.y + v1.z * v1.z + v1.w * v1.w;
#pragma unroll
    for (int m = 1; m < 64; m <<= 1) ss += __shfl_xor(ss, m);
    float sc = rsqrtf(ss * (1.f / 512.f) + 1e-6f);
    float4 s0 = *(const float4*)&scale[l * 8];
    float4 s1 = *(const float4*)&scale[l * 8 + 4];
    ushort8 o;
    o[0] = f2bf(v0.x * sc * s0.x); o[1] = f2bf(v0.y * sc * s0.y);
    o[2] = f2bf(v0.z * sc * s0.z); o[3] = f2bf(v0.w * sc * s0.w);
    o[4] = f2bf(v1.x * sc * s1.x); o[5] = f2bf(v1.y * sc * s1.y);
    o[6] = f2bf(v1.z * sc * s1.z); o[7] = f2bf(v1.w * sc * s1.w);
    *(ushort8*)&xo[row * 512 + l * 8] = o;
}

// ------------------------------------------------------------------
extern "C" void kernel_launch(void* const* d_in, const int* in_sizes, int n_in,
                              void* d_out, int out_size, void* d_ws, size_t ws_size,
                              hipStream_t stream) {
    const float* inputs    = (const float*)d_in[0];
    const void*  mask      = d_in[1];
    const float* carry     = (const float*)d_in[2];
    const float* Wq        = (const float*)d_in[3];
    const float* Wk        = (const float*)d_in[4];
    const float* Wv        = (const float*)d_in[5];
    const float* Wb        = (const float*)d_in[6];
    const float* rms_scale = (const float*)d_in[7];
    const float* Wo        = (const float*)d_in[8];
    const float* bo        = (const float*)d_in[9];

    float* out_carry = (float*)d_out;
    float* out_y     = (float*)d_out + (size_t)B_ * H_ * D_ * D_;

    const int M = M_;  // 2048
    float* ws = (float*)d_ws;
    size_t o = 0;
    float* proj = ws + o; o += (size_t)M * NPROJ;            // 5.37M f
    float* mf   = ws + o; o += (size_t)M;
    float* Ac   = ws + o; o += (size_t)BH * NC * 4096;       // 1M f
    float* Bc   = ws + o; o += (size_t)BH * NC * 4096;       // 1M f
    float* S0   = ws + o; o += (size_t)BH * NC * 4096;       // 1M f
    float* abuf = ws + o; o += (size_t)BH * NC * CL * 128;   // 2M f
    unsigned short* wt   = (unsigned short*)(ws + o); o += (size_t)NPROJ * 512;   // bf16 [NPROJ,1024]
    unsigned short* wo_t = (unsigned short*)(ws + o); o += (size_t)1024 * 256;    // bf16 [1024,512]
    // overlays (lifetimes disjoint):
    unsigned short* inb = (unsigned short*)Bc;   // bf16 inputs, dead before transfer writes Bc
    unsigned short* xbf = (unsigned short*)Ac;   // rms output; Ac dead after combine

    k_mask_prep<<<8, 256, 0, stream>>>(mask, mf, M);
    k_f32_to_bf16<<<(M * 1024) / 1024, 256, 0, stream>>>(inputs, inb, M * 1024);

    // pack all weights (Wq/Wk/Wv/Wb -> wt, Wo -> wo_t) in ONE launch
    k_pack_weights<<<dim3(32, 32, 5), 256, 0, stream>>>(Wq, Wk, Wv, Wb, Wo, wt, wo_t);

    // proj = inputs @ [Wq|Wk|Wv|Wb]
    k_gemm_bf16<<<dim3(NPROJ / 64, M / 128), 256, 0, stream>>>(inb, wt, nullptr, proj, M, NPROJ, 1024);

    // silu+L2norm on q and k, one launch (M*24 groups)
    k_silu_norm2<<<(M * 24) / 4, 256, 0, stream>>>(proj);

    // scan: transfer (+ per-token a,b vectors) -> combine -> X = Aa@S0^T + Bb
    k_chunk_transfer<<<dim3(NC, BH), 1024, 0, stream>>>(proj, mf, Ac, Bc, abuf);
    k_combine<<<BH * 4, 256, 0, stream>>>(Ac, Bc, carry, S0, out_carry);
    k_xgemm<<<dim3(NC, BH), 256, 0, stream>>>(abuf, S0, proj);

    k_rms_bf16<<<M / 4, 256, 0, stream>>>(proj, rms_scale, xbf);

    // y = x @ Wo + bo  (K=512, N=1024)
    k_gemm_bf16<<<dim3(1024 / 64, M / 128), 256, 0, stream>>>(xbf, wo_t, bo, out_y, M, 1024, 512);
}